// Round 12
// baseline (399.572 us; speedup 1.0000x reference)
//
#include <hip/hip_runtime.h>
#include <stdint.h>

#define LOG2E 1.44269504088896340736f

using bf16x8 = __attribute__((ext_vector_type(8))) short;  // 8 bf16 (4 VGPRs)
using f32x4  = __attribute__((ext_vector_type(4))) float;

__device__ __forceinline__ ushort f2bf(float f) {
  union { float f; uint32_t u; } v; v.f = f;
  uint32_t u = v.u;
  u += 0x7FFFu + ((u >> 16) & 1u);   // RNE
  return (ushort)(u >> 16);
}
__device__ __forceinline__ float bf2f(ushort b) {
  union { uint32_t u; float f; } v; v.u = ((uint32_t)b) << 16;
  return v.f;
}
__device__ __forceinline__ uint32_t fbits(float x) {
  union { float f; uint32_t u; } v; v.f = x; return v.u;
}

__device__ __forceinline__ void load_lds16(const void* g, void* l) {
  __builtin_amdgcn_global_load_lds(
      (const __attribute__((address_space(1))) void*)g,
      (__attribute__((address_space(3))) void*)l, 16, 0, 0);
}

// out[row] = dot(mat[row, 0:512], vec[0:512]); 4 rows per 256-thread block
__global__ void rowdot(const float* __restrict__ mat, const float* __restrict__ vec,
                       float* __restrict__ out) {
  int w = threadIdx.x >> 6, l = threadIdx.x & 63;
  int row = blockIdx.x * 4 + w;
  const float4* mp = (const float4*)(mat + row * 512 + l * 8);
  const float4* vp = (const float4*)(vec + l * 8);
  float4 a0 = mp[0], a1 = mp[1];
  float4 b0 = vp[0], b1 = vp[1];
  float d = a0.x * b0.x + a0.y * b0.y + a0.z * b0.z + a0.w * b0.w
          + a1.x * b1.x + a1.y * b1.y + a1.z * b1.z + a1.w * b1.w;
#pragma unroll
  for (int o = 32; o > 0; o >>= 1) d += __shfl_xor(d, o, 64);
  if (l == 0) out[row] = d;
}

__global__ void reduce_max(const float* __restrict__ v, float* __restrict__ outmax) {
  __shared__ float red[4];
  int t = threadIdx.x;
  float m = -3.0e38f;
  for (int j = t; j < 8192; j += 256) m = fmaxf(m, v[j]);
#pragma unroll
  for (int o = 32; o > 0; o >>= 1) m = fmaxf(m, __shfl_xor(m, o, 64));
  if ((t & 63) == 0) red[t >> 6] = m;
  __syncthreads();
  if (t == 0) outmax[0] = fmaxf(fmaxf(red[0], red[1]), fmaxf(red[2], red[3]));
}

// E1[j] = exp2(sm[j]*L), E2[j] = exp2(0.2*sm[j]*L)
__global__ void exp_sm(const float* __restrict__ s_m, float* __restrict__ E1,
                       float* __restrict__ E2) {
  int j = blockIdx.x * 256 + threadIdx.x;
  float v = s_m[j];
  E1[j] = exp2f(v * LOG2E);
  E2[j] = exp2f(v * (0.2f * LOG2E));
}

// A1[i] = exp2((sn-mi)L), A2[i] = exp2((0.2sn-mi)L), mi = lrelu(sn+smax)
__global__ void comp_A(const float* __restrict__ s_n, const float* __restrict__ smaxp,
                       float* __restrict__ A1, float* __restrict__ A2) {
  int i = blockIdx.x * 256 + threadIdx.x;
  float sn = s_n[i];
  float mz = sn + smaxp[0];
  float mi = fmaxf(mz, 0.2f * mz);
  A1[i] = exp2f((sn - mi) * LOG2E);
  A2[i] = exp2f((0.2f * sn - mi) * LOG2E);
}

__global__ void cvt4_bf16(const float* __restrict__ in, ushort* __restrict__ out) {
  int idx = blockIdx.x * 256 + threadIdx.x;
  float4 v = ((const float4*)in)[idx];
  ushort4 o; o.x = f2bf(v.x); o.y = f2bf(v.y); o.z = f2bf(v.z); o.w = f2bf(v.w);
  ((ushort4*)out)[idx] = o;
}

// wT_bf[f][c] = bf16(weight[c][f]); 512x512
__global__ void transpose_w(const float* __restrict__ w, ushort* __restrict__ wT) {
  __shared__ float tile[32][33];
  int t = threadIdx.x; int tx = t & 31, ty = t >> 5;
  int cb = (blockIdx.x & 15) * 32, fb = (blockIdx.x >> 4) * 32;
#pragma unroll
  for (int k = 0; k < 4; ++k) tile[ty + k * 8][tx] = w[(cb + ty + k * 8) * 512 + fb + tx];
  __syncthreads();
#pragma unroll
  for (int k = 0; k < 4; ++k) wT[(fb + ty + k * 8) * 512 + cb + tx] = f2bf(tile[tx][ty + k * 8]);
}

// Whm = neigh @ W in MFMA-B-fragment-packed layout (refchecked in r7):
//   BP[((fb*256 + kc)*64 + lp)*8 + q] = Whm[j][f],
//   fb=f>>4, kc=j>>5, lp=(f&15)+16*((j&31)>>3), q=j&7
__global__ __launch_bounds__(256, 4) void gemm_whmT(const ushort* __restrict__ A,
                                                    const ushort* __restrict__ B,
                                                    ushort* __restrict__ BP) {
  __shared__ ushort At[128 * 32];
  __shared__ ushort Bt2[128 * 32];
  int t = threadIdx.x;
  int j0 = (blockIdx.x >> 2) * 128, f0 = (blockIdx.x & 3) * 128;
  int w = t >> 6, l = t & 63, wr = w >> 1, wc = w & 1;
  f32x4 acc[4][4] = {};
  for (int it = 0; it < 16; ++it) {
    int k0 = it * 32;
#pragma unroll
    for (int c = 0; c < 2; ++c) {
      int u = c * 256 + t; int rr = u >> 2, p = u & 3;
      int sg = p ^ ((rr >> 1) & 3);
      load_lds16(A + (j0 + rr) * 512 + k0 + sg * 8, At + (c * 256 + (t & ~63)) * 8);
      load_lds16(B + (f0 + rr) * 512 + k0 + sg * 8, Bt2 + (c * 256 + (t & ~63)) * 8);
    }
    __syncthreads();
    bf16x8 af[4], bfr[4];
#pragma unroll
    for (int m = 0; m < 4; ++m) {
      int rr = wr * 64 + m * 16 + (l & 15);
      int q = (l >> 4) ^ ((rr >> 1) & 3);
      af[m] = *(const bf16x8*)(At + rr * 32 + q * 8);
    }
#pragma unroll
    for (int n = 0; n < 4; ++n) {
      int rb = wc * 64 + n * 16 + (l & 15);
      int q = (l >> 4) ^ ((rb >> 1) & 3);
      bfr[n] = *(const bf16x8*)(Bt2 + rb * 32 + q * 8);
    }
#pragma unroll
    for (int m = 0; m < 4; ++m)
#pragma unroll
      for (int n = 0; n < 4; ++n)
        acc[m][n] = __builtin_amdgcn_mfma_f32_16x16x32_bf16(af[m], bfr[n], acc[m][n], 0, 0, 0);
    __syncthreads();
  }
#pragma unroll
  for (int m = 0; m < 4; ++m)
#pragma unroll
    for (int n = 0; n < 4; ++n) {
      int f  = f0 + wc * 64 + n * 16 + (l & 15);
      int j4 = j0 + wr * 64 + m * 16 + (l >> 4) * 4;   // 4 consecutive j
      size_t slot = ((size_t)(f >> 4) * 256 + (j4 >> 5)) * 64
                  + (f & 15) + 16 * ((j4 >> 3) & 3);
      ushort4 o;
      o.x = f2bf(acc[m][n][0]); o.y = f2bf(acc[m][n][1]);
      o.z = f2bf(acc[m][n][2]); o.w = f2bf(acc[m][n][3]);
      *(ushort4*)(BP + slot * 8 + (j4 & 7)) = o;
    }
}

// ---------------------------------------------------------------------------
// attn_v12: BARRIER-FREE, LDS-FREE. grid 2048 = 128 rblk x 8 s x 2 fh;
// 256 thr = 4 waves, fg = fh*4+w. Each wave owns 32 rows x 64 f x 1024 k:
//   P = mask ? max(A1_i*E1_j, A2_i*E2_j) : 0 computed in-register (A-frags),
//   B frags reg-double-buffered from packed BP (L2-resident per XCD),
//   mask prefetch DEPTH-2 (even/odd sets), E depth-1. 8 MFMA/body, 32 bodies.
// Self-paced waves at 12/CU hide all residual latency.
// ---------------------------------------------------------------------------
__global__ __launch_bounds__(256, 3) void attn_v12(
    const ushort* __restrict__ BP, const int* __restrict__ mask,
    const float* __restrict__ A1f, const float* __restrict__ A2f,
    const float* __restrict__ E1, const float* __restrict__ E2,
    ushort* __restrict__ num, float* __restrict__ den_part) {
  int t = threadIdx.x;
  int bid = blockIdx.x;
  int s = bid & 7;                 // ksplit == XCD under round-robin
  int rblk = (bid >> 3) & 127;
  int fh = bid >> 10;              // 0..1
  int w = t >> 6, l = t & 63, l15 = l & 15, lq = l >> 4;
  int fg = fh * 4 + w;             // 0..7
  int i0 = rblk * 32;
  int kb = s * 1024, kc0 = s * 32;

  float a1[2], a2[2], dacc[2] = {0.f, 0.f};
#pragma unroll
  for (int m = 0; m < 2; ++m) {
    a1[m] = A1f[i0 + m * 16 + l15];
    a2[m] = A2f[i0 + m * 16 + l15];
  }

  const int* mbase = mask + (size_t)(i0 + l15) * 8192 + kb + lq * 8;  // + m*131072
  const float* e1p = E1 + kb + lq * 8;
  const float* e2p = E2 + kb + lq * 8;
  const ushort* bpb = BP + ((size_t)(fg * 4) * 256 + kc0) * 512 + l * 8;  // + n*131072 + it*512

  bf16x8 bA[4], bB[4];
  int4 mA0[2], mA1[2], mB0[2], mB1[2];   // mask depth-2: even(A)/odd(B) sets
  float4 e1a, e1b, e2a, e2b;             // E depth-1
  f32x4 acc[2][4] = {};
  union PkU { uint32_t u[4]; bf16x8 v; };

  // ---- prologue ----
#pragma unroll
  for (int n = 0; n < 4; ++n) bA[n] = *(const bf16x8*)(bpb + n * 131072);
#pragma unroll
  for (int m = 0; m < 2; ++m) {
    mA0[m] = *(const int4*)(mbase + m * 131072);
    mA1[m] = *(const int4*)(mbase + m * 131072 + 4);
    mB0[m] = *(const int4*)(mbase + m * 131072 + 32);
    mB1[m] = *(const int4*)(mbase + m * 131072 + 36);
  }
  e1a = *(const float4*)(e1p);     e1b = *(const float4*)(e1p + 4);
  e2a = *(const float4*)(e2p);     e2b = *(const float4*)(e2p + 4);

  // body IT: prefetch B(IT+1)->BOUT; P from (MK0_,MK1_)+E; reload that mask
  // set for IT+2; reload E for IT+1; 8 MFMA on BIN.
#define BODY(IT_, BIN_, BOUT_, MK0_, MK1_)                                    \
  {                                                                           \
    int itn_ = ((IT_) + 1) & 31;                                              \
    _Pragma("unroll") for (int n = 0; n < 4; ++n)                             \
      BOUT_[n] = *(const bf16x8*)(bpb + n * 131072 + itn_ * 512);             \
    bf16x8 pa[2];                                                             \
    _Pragma("unroll") for (int m = 0; m < 2; ++m) {                           \
      int4 k0_ = MK0_[m], k1_ = MK1_[m];                                      \
      float p0 = k0_.x ? fmaxf(a1[m] * e1a.x, a2[m] * e2a.x) : 0.f;           \
      float p1 = k0_.y ? fmaxf(a1[m] * e1a.y, a2[m] * e2a.y) : 0.f;           \
      float p2 = k0_.z ? fmaxf(a1[m] * e1a.z, a2[m] * e2a.z) : 0.f;           \
      float p3 = k0_.w ? fmaxf(a1[m] * e1a.w, a2[m] * e2a.w) : 0.f;           \
      float p4 = k1_.x ? fmaxf(a1[m] * e1b.x, a2[m] * e2b.x) : 0.f;           \
      float p5 = k1_.y ? fmaxf(a1[m] * e1b.y, a2[m] * e2b.y) : 0.f;           \
      float p6 = k1_.z ? fmaxf(a1[m] * e1b.z, a2[m] * e2b.z) : 0.f;           \
      float p7 = k1_.w ? fmaxf(a1[m] * e1b.w, a2[m] * e2b.w) : 0.f;           \
      if (fg == 0)                                                            \
        dacc[m] += ((p0 + p1) + (p2 + p3)) + ((p4 + p5) + (p6 + p7));         \
      PkU pk;                                                                 \
      pk.u[0] = (fbits(p1) & 0xFFFF0000u) | (fbits(p0) >> 16);                \
      pk.u[1] = (fbits(p3) & 0xFFFF0000u) | (fbits(p2) >> 16);                \
      pk.u[2] = (fbits(p5) & 0xFFFF0000u) | (fbits(p4) >> 16);                \
      pk.u[3] = (fbits(p7) & 0xFFFF0000u) | (fbits(p6) >> 16);                \
      pa[m] = pk.v;                                                           \
    }                                                                         \
    int itm_ = ((IT_) + 2) & 31;                                              \
    _Pragma("unroll") for (int m = 0; m < 2; ++m) {                           \
      MK0_[m] = *(const int4*)(mbase + m * 131072 + itm_ * 32);               \
      MK1_[m] = *(const int4*)(mbase + m * 131072 + itm_ * 32 + 4);           \
    }                                                                         \
    e1a = *(const float4*)(e1p + itn_ * 32);                                  \
    e1b = *(const float4*)(e1p + itn_ * 32 + 4);                              \
    e2a = *(const float4*)(e2p + itn_ * 32);                                  \
    e2b = *(const float4*)(e2p + itn_ * 32 + 4);                              \
    _Pragma("unroll") for (int n = 0; n < 4; ++n) {                           \
      acc[0][n] = __builtin_amdgcn_mfma_f32_16x16x32_bf16(pa[0], BIN_[n],     \
                                                          acc[0][n], 0, 0, 0); \
      acc[1][n] = __builtin_amdgcn_mfma_f32_16x16x32_bf16(pa[1], BIN_[n],     \
                                                          acc[1][n], 0, 0, 0); \
    }                                                                         \
  }

  for (int it2 = 0; it2 < 16; ++it2) {
    BODY(it2 * 2,     bA, bB, mA0, mA1);
    BODY(it2 * 2 + 1, bB, bA, mB0, mB1);
  }
#undef BODY

  // ---- denominator (fg==0 wave only): reduce across lq groups ----
  if (fg == 0) {
#pragma unroll
    for (int m = 0; m < 2; ++m) {
      float d = dacc[m];
      d += __shfl_xor(d, 16, 64);
      d += __shfl_xor(d, 32, 64);
      if (l < 16) den_part[s * 4096 + i0 + m * 16 + l] = d;
    }
  }
  // ---- numerator write, packed [s][i>>2][512][i&3] bf16 ----
#pragma unroll
  for (int m = 0; m < 2; ++m)
#pragma unroll
    for (int n = 0; n < 4; ++n) {
      int ig = rblk * 8 + m * 4 + lq;
      int f = fg * 64 + n * 16 + l15;
      ushort4 o;
      o.x = f2bf(acc[m][n][0]); o.y = f2bf(acc[m][n][1]);
      o.z = f2bf(acc[m][n][2]); o.w = f2bf(acc[m][n][3]);
      *(ushort4*)(num + (((size_t)s * 1024 + ig) * 512 + f) * 4) = o;
    }
}

// den[i] = sum of 8 ksplit partials
__global__ void p_den(const float* __restrict__ den_part, float* __restrict__ den) {
  int i = blockIdx.x * 256 + threadIdx.x;  // 4096
  float d = 0.f;
#pragma unroll
  for (int k = 0; k < 8; ++k) d += den_part[k * 4096 + i];
  den[i] = d;
}

// out[ig*4+r][f] = (sum_s num[s][ig][f][r]) / den[ig*4+r]
__global__ void reduce_out(const ushort* __restrict__ num, const float* __restrict__ den,
                           float* __restrict__ out) {
  int idx = blockIdx.x * 256 + threadIdx.x;  // 524288 threads
  int ig = idx >> 9, f = idx & 511;
  float s0 = 0.f, s1 = 0.f, s2 = 0.f, s3 = 0.f;
#pragma unroll
  for (int s = 0; s < 8; ++s) {
    ushort4 v = *(const ushort4*)(num + (((size_t)s * 1024 + ig) * 512 + f) * 4);
    s0 += bf2f(v.x); s1 += bf2f(v.y); s2 += bf2f(v.z); s3 += bf2f(v.w);
  }
  const float* dp = den + ig * 4;
  float* op = out + (size_t)ig * 4 * 512 + f;
  op[0]       = s0 / dp[0];
  op[512]     = s1 / dp[1];
  op[2 * 512] = s2 / dp[2];
  op[3 * 512] = s3 / dp[3];
}

extern "C" void kernel_launch(void* const* d_in, const int* in_sizes, int n_in,
                              void* d_out, int out_size, void* d_ws, size_t ws_size,
                              hipStream_t stream) {
  const float* node   = (const float*)d_in[0];
  const float* neigh  = (const float*)d_in[1];
  const float* weight = (const float*)d_in[2];
  const float* att    = (const float*)d_in[3];
  const int*   mask   = (const int*)d_in[4];
  float* out = (float*)d_out;

  char* ws = (char*)d_ws;                     // ~50 MB used
  float* fb = (float*)ws;
  float* w_a1    = fb;              // 512
  float* w_a2    = fb + 512;        // 512
  float* s_n     = fb + 1024;       // 4096
  float* s_m     = fb + 5120;       // 8192
  float* smax    = fb + 13312;      // 1 (pad 8)
  float* A1      = fb + 13320;      // 4096
  float* A2      = fb + 17416;      // 4096
  float* E1      = fb + 21512;      // 8192
  float* E2      = fb + 29704;      // 8192
  float* den_part= fb + 37896;      // 32768 (8 x 4096)
  float* den     = fb + 70664;      // 4096
  ushort* wT_bf  = (ushort*)(ws + 512 * 1024);         // 0.5 MB
  ushort* BP     = (ushort*)(ws + 1 * 1024 * 1024);    // 8 MB (packed Whm)
  ushort* num    = (ushort*)(ws + 9 * 1024 * 1024);    // 32 MB (8 slices)
  ushort* neigh_bf = (ushort*)(ws + 41 * 1024 * 1024); // 8 MB scratch

  rowdot<<<128, 256, 0, stream>>>(weight, att, w_a1);
  rowdot<<<128, 256, 0, stream>>>(weight, att + 512, w_a2);
  rowdot<<<1024, 256, 0, stream>>>(node, w_a1, s_n);
  rowdot<<<2048, 256, 0, stream>>>(neigh, w_a2, s_m);
  reduce_max<<<1, 256, 0, stream>>>(s_m, smax);
  exp_sm<<<32, 256, 0, stream>>>(s_m, E1, E2);
  comp_A<<<16, 256, 0, stream>>>(s_n, smax, A1, A2);
  cvt4_bf16<<<4096, 256, 0, stream>>>(neigh, neigh_bf);
  transpose_w<<<256, 256, 0, stream>>>(weight, wT_bf);
  gemm_whmT<<<256, 256, 0, stream>>>(neigh_bf, wT_bf, BP);
  attn_v12<<<2048, 256, 0, stream>>>(BP, mask, A1, A2, E1, E2, num, den_part);
  p_den<<<16, 256, 0, stream>>>(den_part, den);
  reduce_out<<<2048, 256, 0, stream>>>(num, den, out);
}

// Round 13
// 154.677 us; speedup vs baseline: 2.5833x; 2.5833x over previous
//
#include <hip/hip_runtime.h>
#include <stdint.h>

#define LOG2E 1.44269504088896340736f

using bf16x8 = __attribute__((ext_vector_type(8))) short;  // 8 bf16 (4 VGPRs)
using f32x4  = __attribute__((ext_vector_type(4))) float;

__device__ __forceinline__ ushort f2bf(float f) {
  union { float f; uint32_t u; } v; v.f = f;
  uint32_t u = v.u;
  u += 0x7FFFu + ((u >> 16) & 1u);   // RNE
  return (ushort)(u >> 16);
}
__device__ __forceinline__ float bf2f(ushort b) {
  union { uint32_t u; float f; } v; v.u = ((uint32_t)b) << 16;
  return v.f;
}

__device__ __forceinline__ void load_lds16(const void* g, void* l) {
  __builtin_amdgcn_global_load_lds(
      (const __attribute__((address_space(1))) void*)g,
      (__attribute__((address_space(3))) void*)l, 16, 0, 0);
}

// out[row] = dot(mat[row, 0:512], vec[0:512]); 4 rows per 256-thread block
__global__ void rowdot(const float* __restrict__ mat, const float* __restrict__ vec,
                       float* __restrict__ out) {
  int w = threadIdx.x >> 6, l = threadIdx.x & 63;
  int row = blockIdx.x * 4 + w;
  const float4* mp = (const float4*)(mat + row * 512 + l * 8);
  const float4* vp = (const float4*)(vec + l * 8);
  float4 a0 = mp[0], a1 = mp[1];
  float4 b0 = vp[0], b1 = vp[1];
  float d = a0.x * b0.x + a0.y * b0.y + a0.z * b0.z + a0.w * b0.w
          + a1.x * b1.x + a1.y * b1.y + a1.z * b1.z + a1.w * b1.w;
#pragma unroll
  for (int o = 32; o > 0; o >>= 1) d += __shfl_xor(d, o, 64);
  if (l == 0) out[row] = d;
}

__global__ void reduce_max(const float* __restrict__ v, float* __restrict__ outmax) {
  __shared__ float red[4];
  int t = threadIdx.x;
  float m = -3.0e38f;
  for (int j = t; j < 8192; j += 256) m = fmaxf(m, v[j]);
#pragma unroll
  for (int o = 32; o > 0; o >>= 1) m = fmaxf(m, __shfl_xor(m, o, 64));
  if ((t & 63) == 0) red[t >> 6] = m;
  __syncthreads();
  if (t == 0) outmax[0] = fmaxf(fmaxf(red[0], red[1]), fmaxf(red[2], red[3]));
}

// E1[j] = exp2(sm[j]*L), E2[j] = exp2(0.2*sm[j]*L)
__global__ void exp_sm(const float* __restrict__ s_m, float* __restrict__ E1,
                       float* __restrict__ E2) {
  int j = blockIdx.x * 256 + threadIdx.x;
  float v = s_m[j];
  E1[j] = exp2f(v * LOG2E);
  E2[j] = exp2f(v * (0.2f * LOG2E));
}

// A1[i] = exp2((sn-mi)L), A2[i] = exp2((0.2sn-mi)L), mi = lrelu(sn+smax)
__global__ void comp_A(const float* __restrict__ s_n, const float* __restrict__ smaxp,
                       float* __restrict__ A1, float* __restrict__ A2) {
  int i = blockIdx.x * 256 + threadIdx.x;
  float sn = s_n[i];
  float mz = sn + smaxp[0];
  float mi = fmaxf(mz, 0.2f * mz);
  A1[i] = exp2f((sn - mi) * LOG2E);
  A2[i] = exp2f((0.2f * sn - mi) * LOG2E);
}

__global__ void cvt4_bf16(const float* __restrict__ in, ushort* __restrict__ out) {
  int idx = blockIdx.x * 256 + threadIdx.x;
  float4 v = ((const float4*)in)[idx];
  ushort4 o; o.x = f2bf(v.x); o.y = f2bf(v.y); o.z = f2bf(v.z); o.w = f2bf(v.w);
  ((ushort4*)out)[idx] = o;
}

// wT_bf[f][c] = bf16(weight[c][f]); 512x512
__global__ void transpose_w(const float* __restrict__ w, ushort* __restrict__ wT) {
  __shared__ float tile[32][33];
  int t = threadIdx.x; int tx = t & 31, ty = t >> 5;
  int cb = (blockIdx.x & 15) * 32, fb = (blockIdx.x >> 4) * 32;
#pragma unroll
  for (int k = 0; k < 4; ++k) tile[ty + k * 8][tx] = w[(cb + ty + k * 8) * 512 + fb + tx];
  __syncthreads();
#pragma unroll
  for (int k = 0; k < 4; ++k) wT[(fb + ty + k * 8) * 512 + cb + tx] = f2bf(tile[tx][ty + k * 8]);
}

// WhmT[f][j] = sum_c neigh_bf[j][c] * wT_bf[f][c]   (bf16 out, f-major)
__global__ __launch_bounds__(256, 4) void gemm_whmT(const ushort* __restrict__ A,
                                                    const ushort* __restrict__ B,
                                                    ushort* __restrict__ WhmT) {
  __shared__ ushort At[128 * 32];
  __shared__ ushort Bt2[128 * 32];
  int t = threadIdx.x;
  int j0 = (blockIdx.x >> 2) * 128, f0 = (blockIdx.x & 3) * 128;
  int w = t >> 6, l = t & 63, wr = w >> 1, wc = w & 1;
  f32x4 acc[4][4] = {};
  for (int it = 0; it < 16; ++it) {
    int k0 = it * 32;
#pragma unroll
    for (int c = 0; c < 2; ++c) {
      int u = c * 256 + t; int rr = u >> 2, p = u & 3;
      int sg = p ^ ((rr >> 1) & 3);
      load_lds16(A + (j0 + rr) * 512 + k0 + sg * 8, At + (c * 256 + (t & ~63)) * 8);
      load_lds16(B + (f0 + rr) * 512 + k0 + sg * 8, Bt2 + (c * 256 + (t & ~63)) * 8);
    }
    __syncthreads();
    bf16x8 af[4], bfr[4];
#pragma unroll
    for (int m = 0; m < 4; ++m) {
      int rr = wr * 64 + m * 16 + (l & 15);
      int q = (l >> 4) ^ ((rr >> 1) & 3);
      af[m] = *(const bf16x8*)(At + rr * 32 + q * 8);
    }
#pragma unroll
    for (int n = 0; n < 4; ++n) {
      int rb = wc * 64 + n * 16 + (l & 15);
      int q = (l >> 4) ^ ((rb >> 1) & 3);
      bfr[n] = *(const bf16x8*)(Bt2 + rb * 32 + q * 8);
    }
#pragma unroll
    for (int m = 0; m < 4; ++m)
#pragma unroll
      for (int n = 0; n < 4; ++n)
        acc[m][n] = __builtin_amdgcn_mfma_f32_16x16x32_bf16(af[m], bfr[n], acc[m][n], 0, 0, 0);
    __syncthreads();
  }
#pragma unroll
  for (int m = 0; m < 4; ++m)
#pragma unroll
    for (int n = 0; n < 4; ++n) {
      int j = j0 + wr * 64 + m * 16 + (l >> 4) * 4;
      int f = f0 + wc * 64 + n * 16 + (l & 15);
      ushort4 o;
      o.x = f2bf(acc[m][n][0]); o.y = f2bf(acc[m][n][1]);
      o.z = f2bf(acc[m][n][2]); o.w = f2bf(acc[m][n][3]);
      *(ushort4*)(WhmT + f * 8192 + j) = o;
    }
}

// ---------------------------------------------------------------------------
// attn_fused2: grid 4096 = 128 rblk x 2 fh x 16 s; 256 thr (4 waves);
// LDS = At (32KB, P slice in A-frag layout) + Bt dbuf (2x16KB) = 64KB
// -> 2 blocks/CU so phase1 (mask stream) of one block overlaps phase2
// (MFMA) of the other.
// Phase 1: stream mask slice 32x512 (16 int4 upfront), P via tables,
//          write to LDS swizzled; den partials (fh==0 only).
// Phase 2: counted-vmcnt(4) GEMM: A from resident LDS, B dbuf staged,
//          8 MFMA/body, 16 bodies, setprio on MFMA cluster.
// ---------------------------------------------------------------------------
__global__ __launch_bounds__(256, 2) void attn_fused2(
    const int* __restrict__ mask, const float* __restrict__ A1f,
    const float* __restrict__ A2f, const float* __restrict__ E1,
    const float* __restrict__ E2, const ushort* __restrict__ WhmT,
    ushort* __restrict__ num, float* __restrict__ den_part) {
  __shared__ ushort At16[16 * 32 * 32];  // 32 KB: [ks][row][32k] swizzled
  __shared__ ushort Bt[2][256 * 32];     // 32 KB: [f][32k] swizzled, dbuf
  int t = threadIdx.x;
  int bid = blockIdx.x;
  int s = bid & 15;                // k-slice; XCD = bid%8 (fh-pairs share XCD)
  int fh = (bid >> 4) & 1;
  int rblk = bid >> 5;             // 0..127
  int i0 = rblk * 32, kb = s * 512;
  int w = t >> 6, l = t & 63, l15 = l & 15, lq = l >> 4;

  // ================= phase 1: P slice -> LDS =================
  {
    int row = t >> 3, g = t & 7;   // row 0..31, g 0..7
    int i = i0 + row;
    float a1 = A1f[i], a2 = A2f[i];
    const int* mrow = mask + (size_t)i * 8192 + kb + g * 8;
    int4 mka[8], mkb[8];
#pragma unroll
    for (int c = 0; c < 8; ++c) {  // all mask loads upfront
      mka[c] = *(const int4*)(mrow + c * 64);
      mkb[c] = *(const int4*)(mrow + c * 64 + 4);
    }
    const float* e1p = E1 + kb + g * 8;
    const float* e2p = E2 + kb + g * 8;
    float dacc = 0.f;
    int qsw = (g & 3) ^ ((row >> 1) & 3);
    ushort* lbase = &At16[0] + row * 32 + qsw * 8;
    float4 e1a = *(const float4*)(e1p), e1b = *(const float4*)(e1p + 4);
    float4 e2a = *(const float4*)(e2p), e2b = *(const float4*)(e2p + 4);
#pragma unroll
    for (int c = 0; c < 8; ++c) {
      int4 k0 = mka[c], k1 = mkb[c];
      float4 f1a = e1a, f1b = e1b, f2a = e2a, f2b = e2b;
      if (c < 7) {
        e1a = *(const float4*)(e1p + (c + 1) * 64);
        e1b = *(const float4*)(e1p + (c + 1) * 64 + 4);
        e2a = *(const float4*)(e2p + (c + 1) * 64);
        e2b = *(const float4*)(e2p + (c + 1) * 64 + 4);
      }
      float p0 = k0.x ? fmaxf(a1 * f1a.x, a2 * f2a.x) : 0.f;
      float p1 = k0.y ? fmaxf(a1 * f1a.y, a2 * f2a.y) : 0.f;
      float p2 = k0.z ? fmaxf(a1 * f1a.z, a2 * f2a.z) : 0.f;
      float p3 = k0.w ? fmaxf(a1 * f1a.w, a2 * f2a.w) : 0.f;
      float p4 = k1.x ? fmaxf(a1 * f1b.x, a2 * f2b.x) : 0.f;
      float p5 = k1.y ? fmaxf(a1 * f1b.y, a2 * f2b.y) : 0.f;
      float p6 = k1.z ? fmaxf(a1 * f1b.z, a2 * f2b.z) : 0.f;
      float p7 = k1.w ? fmaxf(a1 * f1b.w, a2 * f2b.w) : 0.f;
      ushort b0 = f2bf(p0), b1 = f2bf(p1), b2 = f2bf(p2), b3 = f2bf(p3);
      ushort b4 = f2bf(p4), b5 = f2bf(p5), b6 = f2bf(p6), b7 = f2bf(p7);
      dacc += ((bf2f(b0) + bf2f(b1)) + (bf2f(b2) + bf2f(b3)))
            + ((bf2f(b4) + bf2f(b5)) + (bf2f(b6) + bf2f(b7)));
      int ks = (g >> 2) + c * 2;   // k-step 0..15
      ushort4 o1; o1.x = b0; o1.y = b1; o1.z = b2; o1.w = b3;
      ushort4 o2; o2.x = b4; o2.y = b5; o2.z = b6; o2.w = b7;
      *(ushort4*)(lbase + ks * 1024) = o1;
      *(ushort4*)(lbase + ks * 1024 + 4) = o2;
    }
    dacc += __shfl_xor(dacc, 1, 64);
    dacc += __shfl_xor(dacc, 2, 64);
    dacc += __shfl_xor(dacc, 4, 64);
    if (g == 0 && fh == 0) den_part[s * 4096 + i] = dacc;
  }
  __syncthreads();

  // ================= phase 2: GEMM from LDS A + staged B =================
  f32x4 acc[2][4] = {};
  int qA = lq ^ ((l15 >> 1) & 3);
  const ushort* paB = &At16[0] + l15 * 32 + qA * 8;   // + ks*1024 + m*512
  const ushort* pb0 = &Bt[0][0] + (w * 64 + l15) * 32 + qA * 8;
  const ushort* pb1 = &Bt[1][0] + (w * 64 + l15) * 32 + qA * 8;

#define STAGE_B(BUF_, T_)                                                     \
  {                                                                           \
    int k0_ = kb + (T_) * 32;                                                 \
    ushort* bb_ = BUF_;                                                       \
    _Pragma("unroll") for (int c = 0; c < 4; ++c) {                           \
      int u_ = c * 256 + t; int rr_ = u_ >> 2, p_ = u_ & 3;                   \
      int sg_ = p_ ^ ((rr_ >> 1) & 3);                                        \
      load_lds16(WhmT + (size_t)(fh * 256 + rr_) * 8192 + k0_ + sg_ * 8,      \
                 bb_ + (c * 256 + (t & ~63)) * 8);                            \
    }                                                                         \
  }

#define BODY(IT_, PB_, BN_, DO_STAGE, VMC_)                                   \
  {                                                                           \
    if (DO_STAGE) { STAGE_B(BN_, (IT_) + 1); }                                \
    asm volatile("s_waitcnt vmcnt(" #VMC_ ")" ::: "memory");                  \
    __builtin_amdgcn_s_barrier();                                             \
    bf16x8 af[2];                                                             \
    _Pragma("unroll") for (int m = 0; m < 2; ++m)                             \
      af[m] = *(const bf16x8*)(paB + (IT_) * 1024 + m * 512);                 \
    __builtin_amdgcn_s_setprio(1);                                            \
    _Pragma("unroll") for (int n = 0; n < 4; ++n) {                           \
      bf16x8 bfr = *(const bf16x8*)(PB_ + n * 512);                           \
      _Pragma("unroll") for (int m = 0; m < 2; ++m)                           \
        acc[m][n] = __builtin_amdgcn_mfma_f32_16x16x32_bf16(af[m], bfr,       \
                                                            acc[m][n], 0, 0, 0); \
    }                                                                         \
    __builtin_amdgcn_s_setprio(0);                                            \
    asm volatile("s_barrier" ::: "memory");                                   \
  }

  STAGE_B(&Bt[0][0], 0);
  asm volatile("s_waitcnt vmcnt(0)" ::: "memory");
  __builtin_amdgcn_s_barrier();

  for (int it2 = 0; it2 < 7; ++it2) {
    BODY(it2 * 2,     pb0, &Bt[1][0], true, 4);
    BODY(it2 * 2 + 1, pb1, &Bt[0][0], true, 4);
  }
  BODY(14, pb0, &Bt[1][0], true, 4);
  BODY(15, pb1, &Bt[0][0], false, 0);

  // numerator write, packed [s][i>>2][512][i&3] bf16, 8B/lane full lines
#pragma unroll
  for (int m = 0; m < 2; ++m)
#pragma unroll
    for (int n = 0; n < 4; ++n) {
      int ig = rblk * 8 + m * 4 + lq;
      int f = fh * 256 + w * 64 + n * 16 + l15;
      ushort4 o;
      o.x = f2bf(acc[m][n][0]); o.y = f2bf(acc[m][n][1]);
      o.z = f2bf(acc[m][n][2]); o.w = f2bf(acc[m][n][3]);
      *(ushort4*)(num + (((size_t)s * 1024 + ig) * 512 + f) * 4) = o;
    }
#undef BODY
#undef STAGE_B
}

// den[i] = sum of 16 ksplit partials
__global__ void p_den(const float* __restrict__ den_part, float* __restrict__ den) {
  int i = blockIdx.x * 256 + threadIdx.x;  // 4096
  float d = 0.f;
#pragma unroll
  for (int k = 0; k < 16; ++k) d += den_part[k * 4096 + i];
  den[i] = d;
}

// out[ig*4+r][f] = (sum_s num[s][ig][f][r]) / den[ig*4+r]
__global__ void reduce_out(const ushort* __restrict__ num, const float* __restrict__ den,
                           float* __restrict__ out) {
  int idx = blockIdx.x * 256 + threadIdx.x;  // 524288 threads
  int ig = idx >> 9, f = idx & 511;
  float s0 = 0.f, s1 = 0.f, s2 = 0.f, s3 = 0.f;
#pragma unroll
  for (int s = 0; s < 16; ++s) {
    ushort4 v = *(const ushort4*)(num + (((size_t)s * 1024 + ig) * 512 + f) * 4);
    s0 += bf2f(v.x); s1 += bf2f(v.y); s2 += bf2f(v.z); s3 += bf2f(v.w);
  }
  const float* dp = den + ig * 4;
  float* op = out + (size_t)ig * 4 * 512 + f;
  op[0]       = s0 / dp[0];
  op[512]     = s1 / dp[1];
  op[2 * 512] = s2 / dp[2];
  op[3 * 512] = s3 / dp[3];
}

extern "C" void kernel_launch(void* const* d_in, const int* in_sizes, int n_in,
                              void* d_out, int out_size, void* d_ws, size_t ws_size,
                              hipStream_t stream) {
  const float* node   = (const float*)d_in[0];
  const float* neigh  = (const float*)d_in[1];
  const float* weight = (const float*)d_in[2];
  const float* att    = (const float*)d_in[3];
  const int*   mask   = (const int*)d_in[4];
  float* out = (float*)d_out;

  char* ws = (char*)d_ws;                     // ~82 MB used
  float* fb = (float*)ws;
  float* w_a1    = fb;              // 512
  float* w_a2    = fb + 512;        // 512
  float* s_n     = fb + 1024;       // 4096
  float* s_m     = fb + 5120;       // 8192
  float* smax    = fb + 13312;      // 1 (pad 8)
  float* A1      = fb + 13320;      // 4096
  float* A2      = fb + 17416;      // 4096
  float* E1      = fb + 21512;      // 8192
  float* E2      = fb + 29704;      // 8192
  float* den_part= fb + 37896;      // 65536 (16 x 4096)
  float* den     = fb + 103432;     // 4096
  ushort* wT_bf  = (ushort*)(ws + 512 * 1024);        // 0.5 MB
  ushort* WhmT   = (ushort*)(ws + 1 * 1024 * 1024);   // 8 MB
  ushort* num    = (ushort*)(ws + 9 * 1024 * 1024);   // 64 MB (16 slices)
  ushort* neigh_bf = (ushort*)(ws + 73 * 1024 * 1024); // 8 MB scratch

  rowdot<<<128, 256, 0, stream>>>(weight, att, w_a1);
  rowdot<<<128, 256, 0, stream>>>(weight, att + 512, w_a2);
  rowdot<<<1024, 256, 0, stream>>>(node, w_a1, s_n);
  rowdot<<<2048, 256, 0, stream>>>(neigh, w_a2, s_m);
  reduce_max<<<1, 256, 0, stream>>>(s_m, smax);
  exp_sm<<<32, 256, 0, stream>>>(s_m, E1, E2);
  comp_A<<<16, 256, 0, stream>>>(s_n, smax, A1, A2);
  cvt4_bf16<<<4096, 256, 0, stream>>>(neigh, neigh_bf);
  transpose_w<<<256, 256, 0, stream>>>(weight, wT_bf);
  gemm_whmT<<<256, 256, 0, stream>>>(neigh_bf, wT_bf, WhmT);
  attn_fused2<<<4096, 256, 0, stream>>>(mask, A1, A2, E1, E2, WhmT, num, den_part);
  p_den<<<16, 256, 0, stream>>>(den_part, den);
  reduce_out<<<2048, 256, 0, stream>>>(num, den, out);
}

// Round 14
// 147.021 us; speedup vs baseline: 2.7178x; 1.0521x over previous
//
#include <hip/hip_runtime.h>
#include <stdint.h>

#define LOG2E 1.44269504088896340736f

using bf16x8 = __attribute__((ext_vector_type(8))) short;  // 8 bf16 (4 VGPRs)
using f32x4  = __attribute__((ext_vector_type(4))) float;

__device__ __forceinline__ ushort f2bf(float f) {
  union { float f; uint32_t u; } v; v.f = f;
  uint32_t u = v.u;
  u += 0x7FFFu + ((u >> 16) & 1u);   // RNE
  return (ushort)(u >> 16);
}
__device__ __forceinline__ float bf2f(ushort b) {
  union { uint32_t u; float f; } v; v.u = ((uint32_t)b) << 16;
  return v.f;
}

__device__ __forceinline__ void load_lds16(const void* g, void* l) {
  __builtin_amdgcn_global_load_lds(
      (const __attribute__((address_space(1))) void*)g,
      (__attribute__((address_space(3))) void*)l, 16, 0, 0);
}

// out[row] = dot(mat[row, 0:512], vec[0:512]); 4 rows per 256-thread block
__global__ void rowdot(const float* __restrict__ mat, const float* __restrict__ vec,
                       float* __restrict__ out) {
  int w = threadIdx.x >> 6, l = threadIdx.x & 63;
  int row = blockIdx.x * 4 + w;
  const float4* mp = (const float4*)(mat + row * 512 + l * 8);
  const float4* vp = (const float4*)(vec + l * 8);
  float4 a0 = mp[0], a1 = mp[1];
  float4 b0 = vp[0], b1 = vp[1];
  float d = a0.x * b0.x + a0.y * b0.y + a0.z * b0.z + a0.w * b0.w
          + a1.x * b1.x + a1.y * b1.y + a1.z * b1.z + a1.w * b1.w;
#pragma unroll
  for (int o = 32; o > 0; o >>= 1) d += __shfl_xor(d, o, 64);
  if (l == 0) out[row] = d;
}

__global__ void reduce_max(const float* __restrict__ v, float* __restrict__ outmax) {
  __shared__ float red[4];
  int t = threadIdx.x;
  float m = -3.0e38f;
  for (int j = t; j < 8192; j += 256) m = fmaxf(m, v[j]);
#pragma unroll
  for (int o = 32; o > 0; o >>= 1) m = fmaxf(m, __shfl_xor(m, o, 64));
  if ((t & 63) == 0) red[t >> 6] = m;
  __syncthreads();
  if (t == 0) outmax[0] = fmaxf(fmaxf(red[0], red[1]), fmaxf(red[2], red[3]));
}

// E1[j] = exp2(sm[j]*L), E2[j] = exp2(0.2*sm[j]*L)
__global__ void exp_sm(const float* __restrict__ s_m, float* __restrict__ E1,
                       float* __restrict__ E2) {
  int j = blockIdx.x * 256 + threadIdx.x;
  float v = s_m[j];
  E1[j] = exp2f(v * LOG2E);
  E2[j] = exp2f(v * (0.2f * LOG2E));
}

// A1[i] = exp2((sn-mi)L), A2[i] = exp2((0.2sn-mi)L), mi = lrelu(sn+smax)
__global__ void comp_A(const float* __restrict__ s_n, const float* __restrict__ smaxp,
                       float* __restrict__ A1, float* __restrict__ A2) {
  int i = blockIdx.x * 256 + threadIdx.x;
  float sn = s_n[i];
  float mz = sn + smaxp[0];
  float mi = fmaxf(mz, 0.2f * mz);
  A1[i] = exp2f((sn - mi) * LOG2E);
  A2[i] = exp2f((0.2f * sn - mi) * LOG2E);
}

__global__ void cvt4_bf16(const float* __restrict__ in, ushort* __restrict__ out) {
  int idx = blockIdx.x * 256 + threadIdx.x;
  float4 v = ((const float4*)in)[idx];
  ushort4 o; o.x = f2bf(v.x); o.y = f2bf(v.y); o.z = f2bf(v.z); o.w = f2bf(v.w);
  ((ushort4*)out)[idx] = o;
}

// wT_bf[f][c] = bf16(weight[c][f]); 512x512
__global__ void transpose_w(const float* __restrict__ w, ushort* __restrict__ wT) {
  __shared__ float tile[32][33];
  int t = threadIdx.x; int tx = t & 31, ty = t >> 5;
  int cb = (blockIdx.x & 15) * 32, fb = (blockIdx.x >> 4) * 32;
#pragma unroll
  for (int k = 0; k < 4; ++k) tile[ty + k * 8][tx] = w[(cb + ty + k * 8) * 512 + fb + tx];
  __syncthreads();
#pragma unroll
  for (int k = 0; k < 4; ++k) wT[(fb + ty + k * 8) * 512 + cb + tx] = f2bf(tile[tx][ty + k * 8]);
}

// WhmT[f][j] = sum_c neigh_bf[j][c] * wT_bf[f][c]   (bf16 out, f-major)
__global__ __launch_bounds__(256, 4) void gemm_whmT(const ushort* __restrict__ A,
                                                    const ushort* __restrict__ B,
                                                    ushort* __restrict__ WhmT) {
  __shared__ ushort At[128 * 32];
  __shared__ ushort Bt2[128 * 32];
  int t = threadIdx.x;
  int j0 = (blockIdx.x >> 2) * 128, f0 = (blockIdx.x & 3) * 128;
  int w = t >> 6, l = t & 63, wr = w >> 1, wc = w & 1;
  f32x4 acc[4][4] = {};
  for (int it = 0; it < 16; ++it) {
    int k0 = it * 32;
#pragma unroll
    for (int c = 0; c < 2; ++c) {
      int u = c * 256 + t; int rr = u >> 2, p = u & 3;
      int sg = p ^ ((rr >> 1) & 3);
      load_lds16(A + (j0 + rr) * 512 + k0 + sg * 8, At + (c * 256 + (t & ~63)) * 8);
      load_lds16(B + (f0 + rr) * 512 + k0 + sg * 8, Bt2 + (c * 256 + (t & ~63)) * 8);
    }
    __syncthreads();
    bf16x8 af[4], bfr[4];
#pragma unroll
    for (int m = 0; m < 4; ++m) {
      int rr = wr * 64 + m * 16 + (l & 15);
      int q = (l >> 4) ^ ((rr >> 1) & 3);
      af[m] = *(const bf16x8*)(At + rr * 32 + q * 8);
    }
#pragma unroll
    for (int n = 0; n < 4; ++n) {
      int rb = wc * 64 + n * 16 + (l & 15);
      int q = (l >> 4) ^ ((rb >> 1) & 3);
      bfr[n] = *(const bf16x8*)(Bt2 + rb * 32 + q * 8);
    }
#pragma unroll
    for (int m = 0; m < 4; ++m)
#pragma unroll
      for (int n = 0; n < 4; ++n)
        acc[m][n] = __builtin_amdgcn_mfma_f32_16x16x32_bf16(af[m], bfr[n], acc[m][n], 0, 0, 0);
    __syncthreads();
  }
#pragma unroll
  for (int m = 0; m < 4; ++m)
#pragma unroll
    for (int n = 0; n < 4; ++n) {
      int j = j0 + wr * 64 + m * 16 + (l >> 4) * 4;
      int f = f0 + wc * 64 + n * 16 + (l & 15);
      ushort4 o;
      o.x = f2bf(acc[m][n][0]); o.y = f2bf(acc[m][n][1]);
      o.z = f2bf(acc[m][n][2]); o.w = f2bf(acc[m][n][3]);
      *(ushort4*)(WhmT + f * 8192 + j) = o;
    }
}

// ---------------------------------------------------------------------------
// attn_v14: r6's fused skeleton at 4 blocks/CU. BM=32, BN=256, BK=32,
// grid 2048 = 128 rblk x 2 fh x 8 s; 256 thr (4 waves); LDS 36 KB.
// Per body: stage B(it+1) [4x load_lds16]; P(it+1) from table pair (compiler
// inserts counted vmcnt, which also retires stage(it+1)-1); reissue pair(it+2);
// lgkm+barrier; 2 A-frags + 4 B-frags ds_read; 8 MFMA; barrier. No setprio.
//   P = mask ? max(A1_i*E1_j, A2_i*E2_j) : 0
// ---------------------------------------------------------------------------
__global__ __launch_bounds__(256, 4) void attn_v14(
    const int* __restrict__ mask, const float* __restrict__ A1f,
    const float* __restrict__ A2f, const float* __restrict__ E1,
    const float* __restrict__ E2, const ushort* __restrict__ WhmT,
    ushort* __restrict__ num, float* __restrict__ den_part) {
  __shared__ ushort Bt[2][256 * 32];  // 2 x 16 KB, xor-swizzled [f][32k]
  __shared__ ushort Pt[2][32 * 32];   // 2 x 2 KB, xor-swizzled [i][32k]
  int t = threadIdx.x;
  int bid = blockIdx.x;
  int s = bid & 7;                 // ksplit == XCD under round-robin
  int fh = (bid >> 3) & 1;
  int rblk = bid >> 4;             // 0..127
  int i0 = rblk * 32;
  int kb = s * 1024;
  int w = t >> 6, l = t & 63, l15 = l & 15, lq = l >> 4;
  int i_loc = t >> 3, jt = t & 7;  // P phase: row 0..31, 8 thr x 4 j each

  float a1 = A1f[i0 + i_loc], a2 = A2f[i0 + i_loc];
  float dacc = 0.f;
  f32x4 acc[2][4] = {};

  // P write addrs (4 bf16/thread, xor-swizzled 16B groups)
  int psP = (jt >> 1) ^ ((i_loc >> 1) & 3);
  ushort* pw0 = &Pt[0][0] + i_loc * 32 + psP * 8 + (jt & 1) * 4;
  ushort* pw1 = &Pt[1][0] + i_loc * 32 + psP * 8 + (jt & 1) * 4;
  // frag read bases
  int qA = lq ^ ((l15 >> 1) & 3);
  const ushort* pa0 = &Pt[0][0] + l15 * 32 + qA * 8;
  const ushort* pa1 = &Pt[1][0] + l15 * 32 + qA * 8;
  const ushort* pb0 = &Bt[0][0] + (w * 64 + l15) * 32 + qA * 8;
  const ushort* pb1 = &Bt[1][0] + (w * 64 + l15) * 32 + qA * 8;

  const int* mrow = mask + (size_t)(i0 + i_loc) * 8192 + kb + jt * 4;
  const float* e1p = E1 + kb + jt * 4;
  const float* e2p = E2 + kb + jt * 4;

#define STAGE_B(BUF_, T_)                                                     \
  {                                                                           \
    int k0_ = kb + (T_) * 32;                                                 \
    ushort* bb_ = BUF_;                                                       \
    _Pragma("unroll") for (int c = 0; c < 4; ++c) {                           \
      int u_ = c * 256 + t; int rr_ = u_ >> 2, p_ = u_ & 3;                   \
      int sg_ = p_ ^ ((rr_ >> 1) & 3);                                        \
      load_lds16(WhmT + (size_t)(fh * 256 + rr_) * 8192 + k0_ + sg_ * 8,      \
                 bb_ + (c * 256 + (t & ~63)) * 8);                            \
    }                                                                         \
  }

#define P_COMP(mkv, e1v, e2v, pdst)                                           \
  {                                                                           \
    float p0 = (mkv).x ? fmaxf(a1 * (e1v).x, a2 * (e2v).x) : 0.f;             \
    float p1 = (mkv).y ? fmaxf(a1 * (e1v).y, a2 * (e2v).y) : 0.f;             \
    float p2 = (mkv).z ? fmaxf(a1 * (e1v).z, a2 * (e2v).z) : 0.f;             \
    float p3 = (mkv).w ? fmaxf(a1 * (e1v).w, a2 * (e2v).w) : 0.f;             \
    ushort4 pv;                                                               \
    pv.x = f2bf(p0); pv.y = f2bf(p1); pv.z = f2bf(p2); pv.w = f2bf(p3);       \
    dacc += bf2f(pv.x) + bf2f(pv.y) + bf2f(pv.z) + bf2f(pv.w);                \
    *(ushort4*)(pdst) = pv;                                                   \
  }

#define BODY(IT_, PA_, PB_, PW_, NXTB_, DO_P, DO_STAGE, LASTWAIT)             \
  {                                                                           \
    if (DO_STAGE) { STAGE_B(NXTB_, (IT_) + 1); }                              \
    if (DO_P) { P_COMP(mkR, e1R, e2R, PW_); }                                 \
    if (DO_STAGE) {                                                           \
      int kM_ = (((IT_) + 2) & 31) * 32;                                      \
      mkR = *(const int4*)(mrow + kM_);                                       \
      e1R = *(const float4*)(e1p + kM_);                                      \
      e2R = *(const float4*)(e2p + kM_);                                      \
    }                                                                         \
    __builtin_amdgcn_sched_barrier(0);                                        \
    if (LASTWAIT) { asm volatile("s_waitcnt vmcnt(0)" ::: "memory"); }        \
    asm volatile("s_waitcnt lgkmcnt(0)\n\ts_barrier" ::: "memory");           \
    __builtin_amdgcn_sched_barrier(0);                                        \
    bf16x8 af[2];                                                             \
    _Pragma("unroll") for (int m = 0; m < 2; ++m)                             \
      af[m] = *(const bf16x8*)(PA_ + m * 512);                                \
    _Pragma("unroll") for (int n = 0; n < 4; ++n) {                           \
      bf16x8 bfr = *(const bf16x8*)(PB_ + n * 512);                           \
      _Pragma("unroll") for (int m = 0; m < 2; ++m)                           \
        acc[m][n] = __builtin_amdgcn_mfma_f32_16x16x32_bf16(af[m], bfr,       \
                                                            acc[m][n], 0, 0, 0); \
    }                                                                         \
    asm volatile("s_barrier" ::: "memory");                                   \
  }

  // ---- prologue: stage(0); P(0) direct; issue pair(1); barrier ----
  STAGE_B(&Bt[0][0], 0);
  int4 mkR; float4 e1R, e2R;
  {
    int4 mk0 = *(const int4*)(mrow);
    float4 ea = *(const float4*)(e1p);
    float4 eb = *(const float4*)(e2p);
    P_COMP(mk0, ea, eb, pw0);
  }
  mkR = *(const int4*)(mrow + 32);
  e1R = *(const float4*)(e1p + 32);
  e2R = *(const float4*)(e2p + 32);
  __builtin_amdgcn_sched_barrier(0);
  asm volatile("s_waitcnt lgkmcnt(0)\n\ts_barrier" ::: "memory");
  __builtin_amdgcn_sched_barrier(0);

  // ---- main loop: 32 K-steps, unrolled by 2 ----
  for (int it2 = 0; it2 < 15; ++it2) {
    int it = it2 * 2;
    BODY(it,     pa0, pb0, pw1, &Bt[1][0], true, true, false);
    BODY(it + 1, pa1, pb1, pw0, &Bt[0][0], true, true, false);
  }
  BODY(30, pa0, pb0, pw1, &Bt[1][0], true, true, false);
  BODY(31, pa1, pb1, pw0, &Bt[0][0], false, false, true);

  // ---- denominator (fh==0 only): reduce across the 8 jt lanes per row ----
  dacc += __shfl_xor(dacc, 1, 64);
  dacc += __shfl_xor(dacc, 2, 64);
  dacc += __shfl_xor(dacc, 4, 64);
  if (jt == 0 && fh == 0) den_part[s * 4096 + i0 + i_loc] = dacc;
  // ---- numerator write, packed [s][i>>2][512][i&3] bf16 ----
#pragma unroll
  for (int m = 0; m < 2; ++m)
#pragma unroll
    for (int n = 0; n < 4; ++n) {
      int ig = rblk * 8 + m * 4 + lq;
      int f = fh * 256 + w * 64 + n * 16 + l15;
      ushort4 o;
      o.x = f2bf(acc[m][n][0]); o.y = f2bf(acc[m][n][1]);
      o.z = f2bf(acc[m][n][2]); o.w = f2bf(acc[m][n][3]);
      *(ushort4*)(num + (((size_t)s * 1024 + ig) * 512 + f) * 4) = o;
    }
#undef BODY
#undef P_COMP
#undef STAGE_B
}

// out[ig*4+r][f] = (sum_s num[s][ig][f][r]) / (sum_s den_part[s][ig*4+r])
__global__ void reduce_out(const ushort* __restrict__ num, const float* __restrict__ den_part,
                           float* __restrict__ out) {
  int idx = blockIdx.x * 256 + threadIdx.x;  // 524288 threads
  int ig = idx >> 9, f = idx & 511;
  float s0 = 0.f, s1 = 0.f, s2 = 0.f, s3 = 0.f;
#pragma unroll
  for (int s = 0; s < 8; ++s) {
    ushort4 v = *(const ushort4*)(num + (((size_t)s * 1024 + ig) * 512 + f) * 4);
    s0 += bf2f(v.x); s1 += bf2f(v.y); s2 += bf2f(v.z); s3 += bf2f(v.w);
  }
  float d0 = 0.f, d1 = 0.f, d2 = 0.f, d3 = 0.f;
#pragma unroll
  for (int s = 0; s < 8; ++s) {
    const float* dp = den_part + s * 4096 + ig * 4;
    d0 += dp[0]; d1 += dp[1]; d2 += dp[2]; d3 += dp[3];
  }
  float* op = out + (size_t)ig * 4 * 512 + f;
  op[0]       = s0 / d0;
  op[512]     = s1 / d1;
  op[2 * 512] = s2 / d2;
  op[3 * 512] = s3 / d3;
}

extern "C" void kernel_launch(void* const* d_in, const int* in_sizes, int n_in,
                              void* d_out, int out_size, void* d_ws, size_t ws_size,
                              hipStream_t stream) {
  const float* node   = (const float*)d_in[0];
  const float* neigh  = (const float*)d_in[1];
  const float* weight = (const float*)d_in[2];
  const float* att    = (const float*)d_in[3];
  const int*   mask   = (const int*)d_in[4];
  float* out = (float*)d_out;

  char* ws = (char*)d_ws;                     // ~50 MB used
  float* fb = (float*)ws;
  float* w_a1    = fb;              // 512
  float* w_a2    = fb + 512;        // 512
  float* s_n     = fb + 1024;       // 4096
  float* s_m     = fb + 5120;       // 8192
  float* smax    = fb + 13312;      // 1 (pad 8)
  float* A1      = fb + 13320;      // 4096
  float* A2      = fb + 17416;      // 4096
  float* E1      = fb + 21512;      // 8192
  float* E2      = fb + 29704;      // 8192
  float* den_part= fb + 37896;      // 32768 (8 x 4096)
  ushort* wT_bf  = (ushort*)(ws + 512 * 1024);         // 0.5 MB
  ushort* WhmT   = (ushort*)(ws + 1 * 1024 * 1024);    // 8 MB
  ushort* num    = (ushort*)(ws + 9 * 1024 * 1024);    // 32 MB (8 slices)
  ushort* neigh_bf = (ushort*)(ws + 41 * 1024 * 1024); // 8 MB scratch

  rowdot<<<128, 256, 0, stream>>>(weight, att, w_a1);
  rowdot<<<128, 256, 0, stream>>>(weight, att + 512, w_a2);
  rowdot<<<1024, 256, 0, stream>>>(node, w_a1, s_n);
  rowdot<<<2048, 256, 0, stream>>>(neigh, w_a2, s_m);
  reduce_max<<<1, 256, 0, stream>>>(s_m, smax);
  exp_sm<<<32, 256, 0, stream>>>(s_m, E1, E2);
  comp_A<<<16, 256, 0, stream>>>(s_n, smax, A1, A2);
  cvt4_bf16<<<4096, 256, 0, stream>>>(neigh, neigh_bf);
  transpose_w<<<256, 256, 0, stream>>>(weight, wT_bf);
  gemm_whmT<<<256, 256, 0, stream>>>(neigh_bf, wT_bf, WhmT);
  attn_v14<<<2048, 256, 0, stream>>>(mask, A1, A2, E1, E2, WhmT, num, den_part);
  reduce_out<<<2048, 256, 0, stream>>>(num, den_part, out);
}